// Round 2
// baseline (328.262 us; speedup 1.0000x reference)
//
#include <hip/hip_runtime.h>

// INRF fused:  out[b,ij,c] = sum_pq [ M2[ij,pq]*x[b,pq,c] - W2[ij,pq]*relu(x[b,pq,c] - S[b,pq,ij,c]) ]
//   S[b,pq,ij,f] = sum_k patch(x)[b,pq,k] * G[ij,k,f]   (3x3 SAME conv, K=144->pad 160)
//
// Round-2 restructure: A-traffic invariant is 1.31MB * (1024/ij_per_block).
//   Was 4 ij/block -> 335 MB L2 traffic (22 us/CU of L2->CU transfer = the stall).
//   Now 64 ij/block (8 ij/wave in regs, 8 waves share LDS-staged A chunks) -> 21 MB.
//   Blocks: 16 ij-groups x 16 tile-groups (16 tiles each). 4 blocks/output element ->
//   out zeroed in build_A, partials combined via atomicAdd (fp32, ~ULP reorder error).
//   Staging: global_load_lds width-16, 2-phase LDS double-buffer (CH=4 tiles/chunk).

typedef __attribute__((ext_vector_type(8))) short bf16x8;
typedef __attribute__((ext_vector_type(4))) float f32x4;

__device__ inline unsigned short f2bf(float x) {
    unsigned u = __float_as_uint(x);
    u += 0x7FFFu + ((u >> 16) & 1u);          // round-to-nearest-even
    return (unsigned short)(u >> 16);
}
__device__ inline unsigned pack2(float a, float b) {
    return (unsigned)f2bf(a) | ((unsigned)f2bf(b) << 16);
}

__device__ inline void gld_lds16(const void* g, void* l) {
    __builtin_amdgcn_global_load_lds((const __attribute__((address_space(1))) void*)g,
                                     (__attribute__((address_space(3))) void*)l, 16, 0, 0);
}

// ---------------- Phase 1: im2col A (frag-swizzled bf16) + Xf (C-frag x) + zero(out) ----
// unit u = tid>>12:
//   u in [0,18): tap = u>>1, h = u&1 -> one uint4 (8 bf16 ch) at quad=(tap&1)*2+h, kk=tap>>1
//   u == 18,19 : zero-pad kk=4, quads 2,3
//   u in [20,24): Xf C-frag gather, one float4 per (tile, lane)
//   u in [24,28): zero out (16384 float4)
__global__ __launch_bounds__(256) void build_A(const float* __restrict__ inp,
                                               uint4* __restrict__ A,
                                               float4* __restrict__ Xf,
                                               float4* __restrict__ outz) {
    const int tid = blockIdx.x * 256 + threadIdx.x;
    const int u = tid >> 12;
    if (u >= 24) {
        outz[tid - 98304] = (float4){0.f, 0.f, 0.f, 0.f};
        return;
    }
    if (u >= 20) {
        const int idx = tid - 81920;          // 0..16383
        const int tile = idx >> 6;
        const int ll = idx & 63;
        const int rowb = tile * 16 + (ll >> 4) * 4;
        const int col = ll & 15;
        float4 v;
        v.x = inp[(rowb + 0) * 16 + col];
        v.y = inp[(rowb + 1) * 16 + col];
        v.z = inp[(rowb + 2) * 16 + col];
        v.w = inp[(rowb + 3) * 16 + col];
        Xf[idx] = v;
        return;
    }
    const int row = tid & 4095;
    const int tile = row >> 4, m = row & 15;
    if (u >= 18) {                            // zero-pad k=144..159 (kk=4, quads 2,3)
        const uint4 z = {0, 0, 0, 0};
        A[(tile * 5 + 4) * 64 + (u - 16) * 16 + m] = z;
        return;
    }
    const int tap = u >> 1, h = u & 1;
    const int dh = tap / 3, dw = tap - dh * 3;
    const int b = row >> 10, pq = row & 1023;
    const int p = pq >> 5, q = pq & 31;
    const int pp = p + dh - 1, qq = q + dw - 1;
    const int kk = tap >> 1, quad = (tap & 1) * 2 + h;
    uint4 o = {0, 0, 0, 0};
    if (((unsigned)pp < 32u) && ((unsigned)qq < 32u)) {
        const float4* s = (const float4*)(inp + b * 16384 + (pp * 32 + qq) * 16 + 8 * h);
        const float4 f0 = s[0], f1 = s[1];
        o.x = pack2(f0.x, f0.y); o.y = pack2(f0.z, f0.w);
        o.z = pack2(f1.x, f1.y); o.w = pack2(f1.z, f1.w);
    }
    A[(tile * 5 + kk) * 64 + quad * 16 + m] = o;
}

// ---------------- Phase 2: 256 blocks x 512 thr; 64 ij/block (8/wave), 16 tiles/block ---
__global__ __launch_bounds__(512, 2) void inrf_main(
    const float* __restrict__ M,     // (1024 ij, 1024 pq)
    const float* __restrict__ Wp,    // (1024 ij, 1024 pq)
    const float* __restrict__ G,     // (1024 ij, 144 k, 16 f)
    const uint4* __restrict__ Aw,    // swizzled bf16 patches, frag (tile,kk) at [..]*64+l
    const float4* __restrict__ Xf,   // x in C-frag layout
    float* __restrict__ out)         // (4,1024,16), pre-zeroed
{
    const int bid = blockIdx.x;
    const int ijblk = bid & 15;       // 16 ij-groups of 64
    const int tgrp  = bid >> 4;       // 16 tile-groups of 16 tiles
    const int tile0 = tgrp * 16;
    const int bb    = tile0 >> 6;     // batch (16-tile groups never cross batches)

    const int t = threadIdx.x, l = t & 63, w = t >> 6;   // 8 waves
    const int quad = l >> 4, col = l & 15;

    __shared__ __align__(16) uint4  Ab[2][4][5][64];   // 2 x (4 tiles x 5 kk) frags
    __shared__ __align__(16) float4 Xb[2][4][64];      // 2 x (4 tiles) x-frags

    // chunk staging: 24 wave-issues (20 A + 4 Xf), 3 per wave. s wave-uniform.
    auto stage = [&](int buf, int ct0) {
#pragma unroll
        for (int r = 0; r < 3; ++r) {
            const int s = w * 3 + r;
            if (s < 20) {
                const int ct = s / 5, kk = s - ct * 5;
                gld_lds16(&Aw[((ct0 + ct) * 5 + kk) * 64 + l], &Ab[buf][ct][kk][0]);
            } else {
                const int ct = s - 20;
                gld_lds16(&Xf[(ct0 + ct) * 64 + l], &Xb[buf][ct][0]);
            }
        }
    };

    stage(0, tile0);                  // overlap chunk0 latency with Bf init

    // B fragments for this wave's 8 ij, straight from global (once).
    const int ij0 = ijblk * 64 + w * 8;
    bf16x8 Bf[8][5];
#pragma unroll
    for (int ij = 0; ij < 8; ++ij) {
        const float* Gg = G + (ij0 + ij) * 2304;
#pragma unroll
        for (int kk = 0; kk < 5; ++kk) {
            bf16x8 f;
#pragma unroll
            for (int j = 0; j < 8; ++j) {
                const int k = kk * 32 + quad * 8 + j;
                const float v = (k < 144) ? Gg[k * 16 + col] : 0.f;
                f[j] = (short)f2bf(v);
            }
            Bf[ij][kk] = f;
        }
    }

    float accv[8] = {0.f, 0.f, 0.f, 0.f, 0.f, 0.f, 0.f, 0.f};

    asm volatile("s_waitcnt vmcnt(0)" ::: "memory");
    __syncthreads();

    int buf = 0;
#pragma unroll 1
    for (int ph = 0; ph < 4; ++ph) {
        if (ph < 3) stage(buf ^ 1, tile0 + (ph + 1) * 4);
#pragma unroll
        for (int ct = 0; ct < 4; ++ct) {
            const int tg = tile0 + ph * 4 + ct;
            uint4 Af[5];
#pragma unroll
            for (int kk = 0; kk < 5; ++kk) Af[kk] = Ab[buf][ct][kk][l];   // ds_read_b128
            const float4 vr = Xb[buf][ct][l];
            const int pqb = (tg & 63) * 16 + quad * 4;
            // two halves of 4 ij: one A-frag read feeds 8 ij of MFMA
#pragma unroll
            for (int h = 0; h < 2; ++h) {
                f32x4 C[4];
#pragma unroll
                for (int jj = 0; jj < 4; ++jj) C[jj] = (f32x4){0.f, 0.f, 0.f, 0.f};
#pragma unroll
                for (int kk = 0; kk < 5; ++kk) {
                    const bf16x8 a = __builtin_bit_cast(bf16x8, Af[kk]);
#pragma unroll
                    for (int jj = 0; jj < 4; ++jj)
                        C[jj] = __builtin_amdgcn_mfma_f32_16x16x32_bf16(
                                    a, Bf[h * 4 + jj][kk], C[jj], 0, 0, 0);
                }
#pragma unroll
                for (int jj = 0; jj < 4; ++jj) {
                    const int ijg = ij0 + h * 4 + jj;
                    const float4 w2 = *(const float4*)&Wp[ijg * 1024 + pqb];
                    const float4 m2 = *(const float4*)&M [ijg * 1024 + pqb];
                    float a0 = accv[h * 4 + jj];
                    a0 += m2.x * vr.x - w2.x * fmaxf(vr.x - C[jj][0], 0.f);
                    a0 += m2.y * vr.y - w2.y * fmaxf(vr.y - C[jj][1], 0.f);
                    a0 += m2.z * vr.z - w2.z * fmaxf(vr.z - C[jj][2], 0.f);
                    a0 += m2.w * vr.w - w2.w * fmaxf(vr.w - C[jj][3], 0.f);
                    accv[h * 4 + jj] = a0;
                }
            }
        }
        asm volatile("s_waitcnt vmcnt(0)" ::: "memory");
        __syncthreads();
        buf ^= 1;
    }

    // quad-reduce -> 16 cols per ij; 4 tile-group blocks combine via atomicAdd
#pragma unroll
    for (int ij = 0; ij < 8; ++ij) {
        float v = accv[ij];
        v += __shfl_xor(v, 16);
        v += __shfl_xor(v, 32);
        if (l < 16) atomicAdd(&out[bb * 16384 + (ij0 + ij) * 16 + l], v);
    }
}

extern "C" void kernel_launch(void* const* d_in, const int* in_sizes, int n_in,
                              void* d_out, int out_size, void* d_ws, size_t ws_size,
                              hipStream_t stream) {
    const float* inp = (const float*)d_in[0];   // 65536
    const float* M   = (const float*)d_in[1];   // 1048576
    const float* Wp  = (const float*)d_in[2];   // 1048576
    const float* G   = (const float*)d_in[3];   // 2359296
    float* out = (float*)d_out;

    uint4*  A  = (uint4*)d_ws;                                   // 81920*16B = 1.31 MB
    float4* Xf = (float4*)((char*)d_ws + 81920 * sizeof(uint4)); // +256 KB

    build_A<<<dim3(448), dim3(256), 0, stream>>>(inp, A, Xf, (float4*)out);
    inrf_main<<<dim3(256), dim3(512), 0, stream>>>(M, Wp, G, A, Xf, out);
}

// Round 3
// 101.845 us; speedup vs baseline: 3.2232x; 3.2232x over previous
//
#include <hip/hip_runtime.h>

// INRF fused:  out[b,ij,c] = sum_pq [ M2[ij,pq]*x[b,pq,c] - W2[ij,pq]*relu(x[b,pq,c] - S[b,pq,ij,c]) ]
//   S[b,pq,ij,f] = sum_k patch(x)[b,pq,k] * G[ij,k,f]   (3x3 SAME conv, K=144->pad 160)
//
// Round-3: round-2's 64-ij/block restructure spilled (Bf[8][5]=160 VGPR > 128 cap ->
//   470MB scratch reads + 317MB scratch writes). Keep the reuse idea, drop to 4 ij/wave
//   (proven VGPR=92 in round 1): 512 blocks = 32 ij-groups x 16 tile-groups, 16 tiles/blk,
//   8 waves share LDS-staged A chunks, each wave owns 4 ij. A-traffic still 8x below R1.
//   G pre-packed to bf16 frags (Gf) in prep kernel: 20 coalesced dwordx4 loads/wave
//   replace 160 strided scalar loads + 160 f2bf. ij-group blocks share bid%8 -> same XCD
//   (L2 co-location, ws ~3.2MB/XCD). Partials (4/output) combined via fp32 atomicAdd.

typedef __attribute__((ext_vector_type(8))) short bf16x8;
typedef __attribute__((ext_vector_type(4))) float f32x4;

__device__ inline unsigned short f2bf(float x) {
    unsigned u = __float_as_uint(x);
    u += 0x7FFFu + ((u >> 16) & 1u);          // round-to-nearest-even
    return (unsigned short)(u >> 16);
}
__device__ inline unsigned pack2(float a, float b) {
    return (unsigned)f2bf(a) | ((unsigned)f2bf(b) << 16);
}

__device__ inline void gld_lds16(const void* g, void* l) {
    __builtin_amdgcn_global_load_lds((const __attribute__((address_space(1))) void*)g,
                                     (__attribute__((address_space(3))) void*)l, 16, 0, 0);
}

// ---------------- Phase 1: A (im2col bf16 frags) + Xf (C-frag x) + Gf (bf16 B-frags) ----
// unit u = tid>>12:
//   u in [0,18): A tap = u>>1, h = u&1 -> uint4 at (tile, kk=tap>>1, quad=(tap&1)*2+h, m)
//   u == 18,19 : A zero-pad kk=4, quads 2,3
//   u in [20,24): Xf C-frag gather, one float4 per (tile, lane)
//   u in [24,28): zero out (16384 float4)
//   u in [28,108): Gf pack: one uint4 per (ij, kk, lane)
__global__ __launch_bounds__(256) void build_pre(const float* __restrict__ inp,
                                                 const float* __restrict__ G,
                                                 uint4* __restrict__ A,
                                                 float4* __restrict__ Xf,
                                                 uint4* __restrict__ Gf,
                                                 float4* __restrict__ outz) {
    const int tid = blockIdx.x * 256 + threadIdx.x;
    const int u = tid >> 12;
    if (u >= 28) {                            // G-pack: lane holds G[k=kk*32+quad*8+j][col]
        const int gidx = tid - 114688;        // 0..327679
        const int ijkk = gidx >> 6, l = gidx & 63;
        const int ij = ijkk / 5, kk = ijkk - ij * 5;
        const int quad = l >> 4, col = l & 15;
        const float* Gg = G + ij * 2304;
        float v[8];
#pragma unroll
        for (int j = 0; j < 8; ++j) {
            const int k = kk * 32 + quad * 8 + j;
            v[j] = (k < 144) ? Gg[k * 16 + col] : 0.f;
        }
        uint4 o;
        o.x = pack2(v[0], v[1]); o.y = pack2(v[2], v[3]);
        o.z = pack2(v[4], v[5]); o.w = pack2(v[6], v[7]);
        Gf[ij * 320 + kk * 64 + l] = o;
        return;
    }
    if (u >= 24) {
        outz[tid - 98304] = (float4){0.f, 0.f, 0.f, 0.f};
        return;
    }
    if (u >= 20) {
        const int idx = tid - 81920;          // 0..16383
        const int tile = idx >> 6, ll = idx & 63;
        const int rowb = tile * 16 + (ll >> 4) * 4;
        const int col = ll & 15;
        float4 v;
        v.x = inp[(rowb + 0) * 16 + col];
        v.y = inp[(rowb + 1) * 16 + col];
        v.z = inp[(rowb + 2) * 16 + col];
        v.w = inp[(rowb + 3) * 16 + col];
        Xf[idx] = v;
        return;
    }
    const int row = tid & 4095;
    const int tile = row >> 4, m = row & 15;
    if (u >= 18) {                            // zero-pad k=144..159 (kk=4, quads 2,3)
        const uint4 z = {0, 0, 0, 0};
        A[(tile * 5 + 4) * 64 + (u - 16) * 16 + m] = z;
        return;
    }
    const int tap = u >> 1, h = u & 1;
    const int dh = tap / 3, dw = tap - dh * 3;
    const int b = row >> 10, pq = row & 1023;
    const int p = pq >> 5, q = pq & 31;
    const int pp = p + dh - 1, qq = q + dw - 1;
    const int kk = tap >> 1, quad = (tap & 1) * 2 + h;
    uint4 o = {0, 0, 0, 0};
    if (((unsigned)pp < 32u) && ((unsigned)qq < 32u)) {
        const float4* s = (const float4*)(inp + b * 16384 + (pp * 32 + qq) * 16 + 8 * h);
        const float4 f0 = s[0], f1 = s[1];
        o.x = pack2(f0.x, f0.y); o.y = pack2(f0.z, f0.w);
        o.z = pack2(f1.x, f1.y); o.w = pack2(f1.z, f1.w);
    }
    A[(tile * 5 + kk) * 64 + quad * 16 + m] = o;
}

// ---------------- Phase 2: 512 blocks x 512 thr; 32 ij/block (4/wave), 16 tiles/block ---
__global__ __launch_bounds__(512, 2) void inrf_main(
    const float* __restrict__ M,     // (1024 ij, 1024 pq)
    const float* __restrict__ Wp,    // (1024 ij, 1024 pq)
    const uint4* __restrict__ Gf,    // bf16 B-frags: [ij*320 + kk*64 + lane]
    const uint4* __restrict__ Aw,    // swizzled bf16 patches, frag (tile,kk) at [..]*64+l
    const float4* __restrict__ Xf,   // x in C-frag layout
    float* __restrict__ out)         // (4,1024,16), pre-zeroed
{
    const int bid = blockIdx.x;
    const int ijblk = bid & 31;       // 32 ij-groups of 32 -> bid%8 = ijblk%8 (XCD co-loc)
    const int tgrp  = bid >> 5;       // 16 tile-groups of 16 tiles
    const int tile0 = tgrp * 16;
    const int bb    = tgrp >> 2;      // batch (16-tile groups never cross batches)

    const int t = threadIdx.x, l = t & 63, w = t >> 6;   // 8 waves
    const int quad = l >> 4;

    __shared__ __align__(16) uint4  Ab[2][4][5][64];   // 2 x (4 tiles x 5 kk) frags (40KB)
    __shared__ __align__(16) float4 Xb[2][4][64];      // 2 x (4 tiles) x-frags (8KB)

    // chunk staging: 24 wave-issues (20 A + 4 Xf), 3 per wave; dest wave-uniform + l*16B
    auto stage = [&](int buf, int ct0) {
#pragma unroll
        for (int r = 0; r < 3; ++r) {
            const int s = w * 3 + r;
            if (s < 20) {
                const int ct = s / 5, kk = s - ct * 5;
                gld_lds16(&Aw[((ct0 + ct) * 5 + kk) * 64 + l], &Ab[buf][ct][kk][0]);
            } else {
                const int ct = s - 20;
                gld_lds16(&Xf[(ct0 + ct) * 64 + l], &Xb[buf][ct][0]);
            }
        }
    };

    stage(0, tile0);                  // overlap chunk0 latency with Bf load

    // B fragments for this wave's 4 ij: 20 coalesced dwordx4 from Gf (80 VGPR)
    const int ij0 = ijblk * 32 + w * 4;
    bf16x8 Bf[4][5];
#pragma unroll
    for (int ij = 0; ij < 4; ++ij)
#pragma unroll
        for (int kk = 0; kk < 5; ++kk)
            Bf[ij][kk] = __builtin_bit_cast(bf16x8, Gf[(ij0 + ij) * 320 + kk * 64 + l]);

    float accv[4] = {0.f, 0.f, 0.f, 0.f};

    asm volatile("s_waitcnt vmcnt(0)" ::: "memory");
    __syncthreads();

    int buf = 0;
#pragma unroll 1
    for (int ph = 0; ph < 4; ++ph) {
        if (ph < 3) stage(buf ^ 1, tile0 + (ph + 1) * 4);
#pragma unroll
        for (int ct = 0; ct < 4; ++ct) {
            const int tg = tile0 + ph * 4 + ct;
            uint4 Af[5];
#pragma unroll
            for (int kk = 0; kk < 5; ++kk) Af[kk] = Ab[buf][ct][kk][l];   // ds_read_b128
            const float4 vr = Xb[buf][ct][l];

            f32x4 C[4];
#pragma unroll
            for (int jj = 0; jj < 4; ++jj) C[jj] = (f32x4){0.f, 0.f, 0.f, 0.f};
#pragma unroll
            for (int kk = 0; kk < 5; ++kk) {
                const bf16x8 a = __builtin_bit_cast(bf16x8, Af[kk]);
#pragma unroll
                for (int jj = 0; jj < 4; ++jj)
                    C[jj] = __builtin_amdgcn_mfma_f32_16x16x32_bf16(
                                a, Bf[jj][kk], C[jj], 0, 0, 0);
            }

            // fused epilogue: acc += M2*x - W2*relu(x - S); rows pqb..pqb+3
            const int pqb = (tg & 63) * 16 + quad * 4;
#pragma unroll
            for (int jj = 0; jj < 4; ++jj) {
                const int ijg = ij0 + jj;
                const float4 w2 = *(const float4*)&Wp[ijg * 1024 + pqb];
                const float4 m2 = *(const float4*)&M [ijg * 1024 + pqb];
                float a0 = accv[jj];
                a0 += m2.x * vr.x - w2.x * fmaxf(vr.x - C[jj][0], 0.f);
                a0 += m2.y * vr.y - w2.y * fmaxf(vr.y - C[jj][1], 0.f);
                a0 += m2.z * vr.z - w2.z * fmaxf(vr.z - C[jj][2], 0.f);
                a0 += m2.w * vr.w - w2.w * fmaxf(vr.w - C[jj][3], 0.f);
                accv[jj] = a0;
            }
        }
        asm volatile("s_waitcnt vmcnt(0)" ::: "memory");
        __syncthreads();
        buf ^= 1;
    }

    // quad-reduce -> 16 cols per ij; 4 tile-group blocks per batch combine via atomicAdd
#pragma unroll
    for (int jj = 0; jj < 4; ++jj) {
        float v = accv[jj];
        v += __shfl_xor(v, 16);
        v += __shfl_xor(v, 32);
        if (l < 16) atomicAdd(&out[bb * 16384 + (ij0 + jj) * 16 + l], v);
    }
}

extern "C" void kernel_launch(void* const* d_in, const int* in_sizes, int n_in,
                              void* d_out, int out_size, void* d_ws, size_t ws_size,
                              hipStream_t stream) {
    const float* inp = (const float*)d_in[0];   // 65536
    const float* M   = (const float*)d_in[1];   // 1048576
    const float* Wp  = (const float*)d_in[2];   // 1048576
    const float* G   = (const float*)d_in[3];   // 2359296
    float* out = (float*)d_out;

    uint4*  A  = (uint4*)d_ws;                                    // 81920*16B  = 1.31 MB
    float4* Xf = (float4*)((char*)d_ws + 1310720);                // 16384*16B  = 256 KB
    uint4*  Gf = (uint4*)((char*)d_ws + 1572864);                 // 327680*16B = 5.24 MB

    build_pre<<<dim3(1728), dim3(256), 0, stream>>>(inp, G, A, Xf, Gf, (float4*)out);
    inrf_main<<<dim3(512), dim3(512), 0, stream>>>(M, Wp, Gf, A, Xf, out);
}